// Round 3
// baseline (282.365 us; speedup 1.0000x reference)
//
#include <hip/hip_runtime.h>
#include <hip/hip_bf16.h>

// Ensemble Q-network, fused, transposed ([features x batch]).
//   h1^T = relu(W1^T x^T + b1);  acc = W2^T h1^T + b2;  out = W3 . relu(acc)  in-register.
// R2: BT=64, 4 waves/block, 4 blocks/CU (phase-diverse backfill) -> fused 54.8->50.4us.
// R3: counters show MfmaUtil 40 / VALUBusy 46 -> still latency-bound, not pipe-bound.
//     (a) layer-2 pipeline deepened: W2 A-frags 2-deep, hs B-frags 1-deep (rotating
//         register sets, compile-time indices) -> vmcnt/lgkmcnt waits ~0.
//     (b) x-pack fused into the kernel: per-block f32->bf16 into xs LDS (4KB, +1
//         barrier); pack kernel is now weights-only (360 blocks). Removes the 2MB
//         HBM round-trip and most of the serial pack dependency.
//     (c) layer-1 A/bias loads hoisted above the xs barrier; layer-2 first A-frags
//         hoisted above the hs barrier (latency hides under barrier wait).

typedef __attribute__((ext_vector_type(8))) short bf16x8;   // 8 bf16 (4 VGPRs)
typedef __attribute__((ext_vector_type(4))) float f32x4;    // MFMA C/D

#define B_TOTAL 32768
#define NQ 10
#define HDIM 256
#define BT 64

#define W1P_ELEMS (NQ * 16 * 64 * 8)        // [n][mtile16][lane64][j8]
#define W2P_ELEMS (NQ * 8 * 16 * 64 * 8)    // [n][kt8][mtile16][lane64][j8]

__device__ __forceinline__ unsigned short f2bf(float f) {
  unsigned int u = __float_as_uint(f);
  u = u + 0x7FFFu + ((u >> 16) & 1u);
  return (unsigned short)(u >> 16);
}

__device__ __forceinline__ unsigned int pk2bf(float a, float b) {
  union { __hip_bfloat162 h; unsigned int u; } cv;
  cv.h = __float22bfloat162_rn(make_float2(a, b));
  return cv.u;
}

// ---- pack dispatch: weights only (W1^T, W2^T -> MFMA A-frag order) ----
__global__ void pack_w_kernel(const float* __restrict__ W1,
                              const float* __restrict__ W2,
                              unsigned short* __restrict__ w1p,
                              unsigned short* __restrict__ w2p) {
  int t = blockIdx.x * 256 + threadIdx.x;   // 360 * 256 = 92160 exactly
  const int NW1 = NQ * 16 * 64;             // 10240
  if (t < NW1) {
    int u = t;
    int lane = u & 63, mt = (u >> 6) & 15, n = u >> 10;
    int m = lane & 15, q = lane >> 4;
    int outc = mt * 16 + m;
    unsigned short v[8];
#pragma unroll
    for (int j = 0; j < 8; j++) {
      int k = q * 8 + j;
      v[j] = (k < 23) ? f2bf(W1[(n * 23 + k) * 256 + outc]) : (unsigned short)0;
    }
    *(uint4*)&w1p[(size_t)u * 8] = *(const uint4*)v;
  } else {
    int u = t - NW1;                        // < 81920
    int lane = u & 63, mt = (u >> 6) & 15, kt = (u >> 10) & 7, n = u >> 13;
    int m = lane & 15, q = lane >> 4;
    int outc = mt * 16 + m;
    unsigned short v[8];
#pragma unroll
    for (int j = 0; j < 8; j++) {
      int h = kt * 32 + q * 8 + j;
      v[j] = f2bf(W2[((size_t)(n * 256 + h)) * 256 + outc]);
    }
    *(uint4*)&w2p[(size_t)u * 8] = *(const uint4*)v;
  }
}

// ---- fused MLP: 5120 blocks x 256 threads (4 waves), 4 blocks/CU ----
// wave w: channel group = w (64 ch); all waves share the block's 64 batch cols
__global__ __launch_bounds__(256, 4) void fused_ensemble_kernel(
    const float* __restrict__ state,
    const float* __restrict__ action,
    const unsigned short* __restrict__ w1p,
    const float* __restrict__ b1,
    const unsigned short* __restrict__ w2p,
    const float* __restrict__ b2,
    const float* __restrict__ W3,
    const float* __restrict__ b3,
    float* __restrict__ out) {
  __shared__ __align__(16) unsigned short hs[32 * BT * 8];  // 32 KB, [ch/8][col][8]
  __shared__ __align__(16) unsigned short xs[BT * 32];      // 4 KB, [col][32] bf16
  __shared__ float red[4 * 64];                             // 1 KB cross-wave reduce

  const int tid = threadIdx.x;
  const int lane = tid & 63;
  const int w = tid >> 6;       // 0..3: channels [w*64, w*64+64)
  const int m = lane & 15;
  const int q = lane >> 4;

  const int n = blockIdx.x >> 9;            // 512 tiles per net
  const int row0 = (blockIdx.x & 511) * BT;

  f32x4 acc[4][4];   // [mt][nt]: ch = w*64 + mt*16 + q*4 + r, col = nt*16 + m

  // ---- layer-1 A-frags + bias issued first (hide under xs staging + barrier) ----
  bf16x8 af1[4];
#pragma unroll
  for (int mt = 0; mt < 4; mt++)
    af1[mt] = *(const bf16x8*)(w1p + (((size_t)n * 16 + w * 4 + mt) * 64 + lane) * 8);
  float4 b1v[4];
#pragma unroll
  for (int mt = 0; mt < 4; mt++)
    b1v[mt] = *(const float4*)&b1[n * HDIM + (w * 4 + mt) * 16 + q * 4];

  // ---- stage x -> xs (f32 -> bf16, k-padded to 32), replaces the old xp pack ----
  {
    int r = tid >> 2, seg = tid & 3;        // 64 rows x 4 segs of 8
    int row = row0 + r;
    unsigned short v[8];
    if (seg < 2) {
      const float* sp = state + (size_t)row * 17 + seg * 8;
#pragma unroll
      for (int j = 0; j < 8; j++) v[j] = f2bf(sp[j]);
    } else if (seg == 2) {
      v[0] = f2bf(state[(size_t)row * 17 + 16]);
      const float* ap = action + (size_t)row * 6;
#pragma unroll
      for (int j = 0; j < 6; j++) v[1 + j] = f2bf(ap[j]);
      v[7] = 0;
    } else {
#pragma unroll
      for (int j = 0; j < 8; j++) v[j] = 0;
    }
    *(uint4*)&xs[(size_t)r * 32 + seg * 8] = *(const uint4*)v;
  }
  __syncthreads();

  // ---- layer 1: single K-step (K=32, input dim 23 padded) ----
  {
    bf16x8 bfr[4];
#pragma unroll
    for (int nt = 0; nt < 4; nt++)
      bfr[nt] = *(const bf16x8*)&xs[(size_t)(nt * 16 + m) * 32 + q * 8];
#pragma unroll
    for (int mt = 0; mt < 4; mt++) {
      float4 bv = b1v[mt];
      f32x4 bi = (f32x4){bv.x, bv.y, bv.z, bv.w};
#pragma unroll
      for (int nt = 0; nt < 4; nt++) acc[mt][nt] = bi;
    }
    __builtin_amdgcn_s_setprio(1);
#pragma unroll
    for (int nt = 0; nt < 4; nt++)
#pragma unroll
      for (int mt = 0; mt < 4; mt++)
        acc[mt][nt] = __builtin_amdgcn_mfma_f32_16x16x32_bf16(af1[mt], bfr[nt], acc[mt][nt], 0, 0, 0);
    __builtin_amdgcn_s_setprio(0);
  }

  // ---- layer-2 first A-frags + bias issued before the hs barrier ----
  const unsigned short* w2n = w2p + (size_t)n * (8 * 16 * 64 * 8);
  bf16x8 af[3][4];                          // rotating 2-deep A prefetch
#pragma unroll
  for (int mt = 0; mt < 4; mt++)
    af[0][mt] = *(const bf16x8*)(w2n + (((size_t)0 * 16 + w * 4 + mt) * 64 + lane) * 8);
#pragma unroll
  for (int mt = 0; mt < 4; mt++)
    af[1][mt] = *(const bf16x8*)(w2n + (((size_t)1 * 16 + w * 4 + mt) * 64 + lane) * 8);
  float4 b2v[4];
#pragma unroll
  for (int mt = 0; mt < 4; mt++)
    b2v[mt] = *(const float4*)&b2[n * HDIM + (w * 4 + mt) * 16 + q * 4];

  // ---- epilogue 1: relu -> h1 bf16 frag-chunk layout; one b64 per frag ----
#pragma unroll
  for (int mt = 0; mt < 4; mt++) {
    int kq = w * 8 + mt * 2 + (q >> 1);
    int joff = (q & 1) * 4;
#pragma unroll
    for (int nt = 0; nt < 4; nt++) {
      int col = nt * 16 + m;
      f32x4 a = acc[mt][nt];
      uint2 wv;
      wv.x = pk2bf(fmaxf(a[0], 0.f), fmaxf(a[1], 0.f));
      wv.y = pk2bf(fmaxf(a[2], 0.f), fmaxf(a[3], 0.f));
      *(uint2*)&hs[((size_t)kq * BT + col) * 8 + joff] = wv;
    }
  }
  __syncthreads();

  // ---- layer 2: 8 K-steps; A 2-deep from L2, B 1-deep from LDS ----
  {
    bf16x8 bfb[2][4];                       // double-buffered B frags
#pragma unroll
    for (int nt = 0; nt < 4; nt++)
      bfb[0][nt] = *(const bf16x8*)&hs[(((size_t)0 * 4 + q) * BT + nt * 16 + m) * 8];
#pragma unroll
    for (int mt = 0; mt < 4; mt++) {
      float4 bv = b2v[mt];
      f32x4 bi = (f32x4){bv.x, bv.y, bv.z, bv.w};
#pragma unroll
      for (int nt = 0; nt < 4; nt++) acc[mt][nt] = bi;
    }
#pragma unroll
    for (int kt = 0; kt < 8; kt++) {
      if (kt < 6) {
#pragma unroll
        for (int mt = 0; mt < 4; mt++)
          af[(kt + 2) % 3][mt] =
              *(const bf16x8*)(w2n + (((size_t)(kt + 2) * 16 + w * 4 + mt) * 64 + lane) * 8);
      }
      if (kt < 7) {
#pragma unroll
        for (int nt = 0; nt < 4; nt++)
          bfb[(kt + 1) & 1][nt] =
              *(const bf16x8*)&hs[(((size_t)(kt + 1) * 4 + q) * BT + nt * 16 + m) * 8];
      }
      __builtin_amdgcn_s_setprio(1);
#pragma unroll
      for (int nt = 0; nt < 4; nt++)
#pragma unroll
        for (int mt = 0; mt < 4; mt++)
          acc[mt][nt] = __builtin_amdgcn_mfma_f32_16x16x32_bf16(af[kt % 3][mt], bfb[kt & 1][nt],
                                                               acc[mt][nt], 0, 0, 0);
      __builtin_amdgcn_s_setprio(0);
    }
  }

  // ---- layer 3 in-register: p[col] = sum_ch relu(acc_ch) * W3[ch]; reduce ----
  {
    float4 w3v[4];
#pragma unroll
    for (int mt = 0; mt < 4; mt++)
      w3v[mt] = *(const float4*)&W3[n * HDIM + (w * 4 + mt) * 16 + q * 4];
    float p[4];
#pragma unroll
    for (int nt = 0; nt < 4; nt++) {
      float s = 0.f;
#pragma unroll
      for (int mt = 0; mt < 4; mt++) {
        f32x4 a = acc[mt][nt];
        float4 wv = w3v[mt];
        s = fmaf(fmaxf(a[0], 0.f), wv.x, s);
        s = fmaf(fmaxf(a[1], 0.f), wv.y, s);
        s = fmaf(fmaxf(a[2], 0.f), wv.z, s);
        s = fmaf(fmaxf(a[3], 0.f), wv.w, s);
      }
      s += __shfl_xor(s, 16, 64);   // reduce q within wave (channels)
      s += __shfl_xor(s, 32, 64);
      p[nt] = s;
    }
    if (q == 0) {
#pragma unroll
      for (int nt = 0; nt < 4; nt++) red[w * 64 + nt * 16 + m] = p[nt];
    }
    __syncthreads();
    if (tid < BT) {
      float s = b3[n];
#pragma unroll
      for (int c = 0; c < 4; c++) s += red[c * 64 + tid];
      out[(size_t)n * B_TOTAL + row0 + tid] = s;
    }
  }
}

extern "C" void kernel_launch(void* const* d_in, const int* in_sizes, int n_in,
                              void* d_out, int out_size, void* d_ws, size_t ws_size,
                              hipStream_t stream) {
  const float* state  = (const float*)d_in[0];
  const float* action = (const float*)d_in[1];
  const float* W1 = (const float*)d_in[2];
  const float* b1 = (const float*)d_in[3];
  const float* W2 = (const float*)d_in[4];
  const float* b2 = (const float*)d_in[5];
  const float* W3 = (const float*)d_in[6];
  const float* b3 = (const float*)d_in[7];
  float* out = (float*)d_out;

  unsigned short* w1p = (unsigned short*)d_ws;                                    // 163,840 B
  unsigned short* w2p = (unsigned short*)((char*)d_ws + (size_t)W1P_ELEMS * 2);   // 1,310,720 B

  pack_w_kernel<<<360, 256, 0, stream>>>(W1, W2, w1p, w2p);
  fused_ensemble_kernel<<<NQ * (B_TOTAL / BT), 256, 0, stream>>>(
      state, action, w1p, b1, w2p, b2, W3, b3, out);
}

// Round 4
// 119.690 us; speedup vs baseline: 2.3591x; 2.3591x over previous
//
#include <hip/hip_runtime.h>
#include <hip/hip_bf16.h>

// Ensemble Q-network, fused, transposed ([features x batch]).
//   h1^T = relu(W1^T x^T + b1);  acc = W2^T h1^T + b2;  out = W3 . relu(acc)  in-register.
// R2: BT=64, 4 waves/block, 4 blocks/CU (phase-diverse backfill) -> fused 54.8->50.4us.
// R3: FAILED - 2-deep A + 1-deep B pipeline = +80 VGPR over the 64-VGPR budget
//     (launch_bounds(256,4) + 64 AGPR acc caps VGPRs at 64) -> scratch spill,
//     WRITE_SIZE 1.3MB->590MB, 230us. Reverted.
// R4: R2 structure (1-deep A prefetch, fits 64 VGPR) + the register-neutral R3 parts:
//     (a) x staged in-kernel (xs LDS, 4KB; pack kernel is weights-only) - removes
//         the 2MB xp HBM round-trip and the x-pack serial dependency.
//     (b) cheap hoists: af1/b1v before the xs barrier; layer-2 first acur + b2v
//         issued after hs stores but BEFORE __syncthreads (L2 latency hides under
//         the barrier wait, no extra live range vs R2).

typedef __attribute__((ext_vector_type(8))) short bf16x8;   // 8 bf16 (4 VGPRs)
typedef __attribute__((ext_vector_type(4))) float f32x4;    // MFMA C/D

#define B_TOTAL 32768
#define NQ 10
#define HDIM 256
#define BT 64

#define W1P_ELEMS (NQ * 16 * 64 * 8)        // [n][mtile16][lane64][j8]
#define W2P_ELEMS (NQ * 8 * 16 * 64 * 8)    // [n][kt8][mtile16][lane64][j8]

__device__ __forceinline__ unsigned short f2bf(float f) {
  unsigned int u = __float_as_uint(f);
  u = u + 0x7FFFu + ((u >> 16) & 1u);
  return (unsigned short)(u >> 16);
}

__device__ __forceinline__ unsigned int pk2bf(float a, float b) {
  union { __hip_bfloat162 h; unsigned int u; } cv;
  cv.h = __float22bfloat162_rn(make_float2(a, b));
  return cv.u;
}

// ---- pack dispatch: weights only (W1^T, W2^T -> MFMA A-frag order) ----
__global__ void pack_w_kernel(const float* __restrict__ W1,
                              const float* __restrict__ W2,
                              unsigned short* __restrict__ w1p,
                              unsigned short* __restrict__ w2p) {
  int t = blockIdx.x * 256 + threadIdx.x;   // 360 * 256 = 92160 exactly
  const int NW1 = NQ * 16 * 64;             // 10240
  if (t < NW1) {
    int u = t;
    int lane = u & 63, mt = (u >> 6) & 15, n = u >> 10;
    int m = lane & 15, q = lane >> 4;
    int outc = mt * 16 + m;
    unsigned short v[8];
#pragma unroll
    for (int j = 0; j < 8; j++) {
      int k = q * 8 + j;
      v[j] = (k < 23) ? f2bf(W1[(n * 23 + k) * 256 + outc]) : (unsigned short)0;
    }
    *(uint4*)&w1p[(size_t)u * 8] = *(const uint4*)v;
  } else {
    int u = t - NW1;                        // < 81920
    int lane = u & 63, mt = (u >> 6) & 15, kt = (u >> 10) & 7, n = u >> 13;
    int m = lane & 15, q = lane >> 4;
    int outc = mt * 16 + m;
    unsigned short v[8];
#pragma unroll
    for (int j = 0; j < 8; j++) {
      int h = kt * 32 + q * 8 + j;
      v[j] = f2bf(W2[((size_t)(n * 256 + h)) * 256 + outc]);
    }
    *(uint4*)&w2p[(size_t)u * 8] = *(const uint4*)v;
  }
}

// ---- fused MLP: 5120 blocks x 256 threads (4 waves), 4 blocks/CU ----
// wave w: channel group = w (64 ch); all waves share the block's 64 batch cols
__global__ __launch_bounds__(256, 4) void fused_ensemble_kernel(
    const float* __restrict__ state,
    const float* __restrict__ action,
    const unsigned short* __restrict__ w1p,
    const float* __restrict__ b1,
    const unsigned short* __restrict__ w2p,
    const float* __restrict__ b2,
    const float* __restrict__ W3,
    const float* __restrict__ b3,
    float* __restrict__ out) {
  __shared__ __align__(16) unsigned short hs[32 * BT * 8];  // 32 KB, [ch/8][col][8]
  __shared__ __align__(16) unsigned short xs[BT * 32];      // 4 KB, [col][32] bf16
  __shared__ float red[4 * 64];                             // 1 KB cross-wave reduce

  const int tid = threadIdx.x;
  const int lane = tid & 63;
  const int w = tid >> 6;       // 0..3: channels [w*64, w*64+64)
  const int m = lane & 15;
  const int q = lane >> 4;

  const int n = blockIdx.x >> 9;            // 512 tiles per net
  const int row0 = (blockIdx.x & 511) * BT;

  f32x4 acc[4][4];   // [mt][nt]: ch = w*64 + mt*16 + q*4 + r, col = nt*16 + m

  // ---- layer-1 A-frags + bias issued first (hide under xs staging + barrier) ----
  bf16x8 af1[4];
#pragma unroll
  for (int mt = 0; mt < 4; mt++)
    af1[mt] = *(const bf16x8*)(w1p + (((size_t)n * 16 + w * 4 + mt) * 64 + lane) * 8);
  float4 b1v[4];
#pragma unroll
  for (int mt = 0; mt < 4; mt++)
    b1v[mt] = *(const float4*)&b1[n * HDIM + (w * 4 + mt) * 16 + q * 4];

  // ---- stage x -> xs (f32 -> bf16, k-padded to 32) ----
  {
    int r = tid >> 2, seg = tid & 3;        // 64 rows x 4 segs of 8
    int row = row0 + r;
    unsigned short v[8];
    if (seg < 2) {
      const float* sp = state + (size_t)row * 17 + seg * 8;
#pragma unroll
      for (int j = 0; j < 8; j++) v[j] = f2bf(sp[j]);
    } else if (seg == 2) {
      v[0] = f2bf(state[(size_t)row * 17 + 16]);
      const float* ap = action + (size_t)row * 6;
#pragma unroll
      for (int j = 0; j < 6; j++) v[1 + j] = f2bf(ap[j]);
      v[7] = 0;
    } else {
#pragma unroll
      for (int j = 0; j < 8; j++) v[j] = 0;
    }
    *(uint4*)&xs[(size_t)r * 32 + seg * 8] = *(const uint4*)v;
  }
  __syncthreads();

  // ---- layer 1: single K-step (K=32, input dim 23 padded) ----
  {
    bf16x8 bfr[4];
#pragma unroll
    for (int nt = 0; nt < 4; nt++)
      bfr[nt] = *(const bf16x8*)&xs[(size_t)(nt * 16 + m) * 32 + q * 8];
#pragma unroll
    for (int mt = 0; mt < 4; mt++) {
      float4 bv = b1v[mt];
      f32x4 bi = (f32x4){bv.x, bv.y, bv.z, bv.w};
#pragma unroll
      for (int nt = 0; nt < 4; nt++) acc[mt][nt] = bi;
    }
    __builtin_amdgcn_s_setprio(1);
#pragma unroll
    for (int nt = 0; nt < 4; nt++)
#pragma unroll
      for (int mt = 0; mt < 4; mt++)
        acc[mt][nt] = __builtin_amdgcn_mfma_f32_16x16x32_bf16(af1[mt], bfr[nt], acc[mt][nt], 0, 0, 0);
    __builtin_amdgcn_s_setprio(0);
  }

  // ---- epilogue 1: relu -> h1 bf16 frag-chunk layout; one b64 per frag ----
#pragma unroll
  for (int mt = 0; mt < 4; mt++) {
    int kq = w * 8 + mt * 2 + (q >> 1);
    int joff = (q & 1) * 4;
#pragma unroll
    for (int nt = 0; nt < 4; nt++) {
      int col = nt * 16 + m;
      f32x4 a = acc[mt][nt];
      uint2 wv;
      wv.x = pk2bf(fmaxf(a[0], 0.f), fmaxf(a[1], 0.f));
      wv.y = pk2bf(fmaxf(a[2], 0.f), fmaxf(a[3], 0.f));
      *(uint2*)&hs[((size_t)kq * BT + col) * 8 + joff] = wv;
    }
  }

  // ---- layer-2 first A-frags + bias: issue BEFORE the barrier (hide under wait) ----
  const unsigned short* w2n = w2p + (size_t)n * (8 * 16 * 64 * 8);
  bf16x8 acur[4], anxt[4];
#pragma unroll
  for (int mt = 0; mt < 4; mt++)
    acur[mt] = *(const bf16x8*)(w2n + (((size_t)w * 4 + mt) * 64 + lane) * 8);
  float4 b2v[4];
#pragma unroll
  for (int mt = 0; mt < 4; mt++)
    b2v[mt] = *(const float4*)&b2[n * HDIM + (w * 4 + mt) * 16 + q * 4];
  __syncthreads();

  // ---- layer 2: 8 K-steps, A-frags streamed from L2 with 1-deep prefetch ----
  {
#pragma unroll
    for (int mt = 0; mt < 4; mt++) {
      float4 bv = b2v[mt];
      f32x4 bi = (f32x4){bv.x, bv.y, bv.z, bv.w};
#pragma unroll
      for (int nt = 0; nt < 4; nt++) acc[mt][nt] = bi;
    }
#pragma unroll
    for (int kt = 0; kt < 8; kt++) {
      if (kt < 7) {
#pragma unroll
        for (int mt = 0; mt < 4; mt++)
          anxt[mt] = *(const bf16x8*)(w2n + (((size_t)(kt + 1) * 16 + w * 4 + mt) * 64 + lane) * 8);
      }
      bf16x8 bfr[4];
#pragma unroll
      for (int nt = 0; nt < 4; nt++)
        bfr[nt] = *(const bf16x8*)&hs[(((size_t)kt * 4 + q) * BT + nt * 16 + m) * 8];
      __builtin_amdgcn_s_setprio(1);
#pragma unroll
      for (int nt = 0; nt < 4; nt++)
#pragma unroll
        for (int mt = 0; mt < 4; mt++)
          acc[mt][nt] = __builtin_amdgcn_mfma_f32_16x16x32_bf16(acur[mt], bfr[nt], acc[mt][nt], 0, 0, 0);
      __builtin_amdgcn_s_setprio(0);
#pragma unroll
      for (int mt = 0; mt < 4; mt++) acur[mt] = anxt[mt];
    }
  }

  // ---- layer 3 in-register: p[col] = sum_ch relu(acc_ch) * W3[ch]; reduce ----
  {
    float4 w3v[4];
#pragma unroll
    for (int mt = 0; mt < 4; mt++)
      w3v[mt] = *(const float4*)&W3[n * HDIM + (w * 4 + mt) * 16 + q * 4];
    float p[4];
#pragma unroll
    for (int nt = 0; nt < 4; nt++) {
      float s = 0.f;
#pragma unroll
      for (int mt = 0; mt < 4; mt++) {
        f32x4 a = acc[mt][nt];
        float4 wv = w3v[mt];
        s = fmaf(fmaxf(a[0], 0.f), wv.x, s);
        s = fmaf(fmaxf(a[1], 0.f), wv.y, s);
        s = fmaf(fmaxf(a[2], 0.f), wv.z, s);
        s = fmaf(fmaxf(a[3], 0.f), wv.w, s);
      }
      s += __shfl_xor(s, 16, 64);   // reduce q within wave (channels)
      s += __shfl_xor(s, 32, 64);
      p[nt] = s;
    }
    if (q == 0) {
#pragma unroll
      for (int nt = 0; nt < 4; nt++) red[w * 64 + nt * 16 + m] = p[nt];
    }
    __syncthreads();
    if (tid < BT) {
      float s = b3[n];
#pragma unroll
      for (int c = 0; c < 4; c++) s += red[c * 64 + tid];
      out[(size_t)n * B_TOTAL + row0 + tid] = s;
    }
  }
}

extern "C" void kernel_launch(void* const* d_in, const int* in_sizes, int n_in,
                              void* d_out, int out_size, void* d_ws, size_t ws_size,
                              hipStream_t stream) {
  const float* state  = (const float*)d_in[0];
  const float* action = (const float*)d_in[1];
  const float* W1 = (const float*)d_in[2];
  const float* b1 = (const float*)d_in[3];
  const float* W2 = (const float*)d_in[4];
  const float* b2 = (const float*)d_in[5];
  const float* W3 = (const float*)d_in[6];
  const float* b3 = (const float*)d_in[7];
  float* out = (float*)d_out;

  unsigned short* w1p = (unsigned short*)d_ws;                                    // 163,840 B
  unsigned short* w2p = (unsigned short*)((char*)d_ws + (size_t)W1P_ELEMS * 2);   // 1,310,720 B

  pack_w_kernel<<<360, 256, 0, stream>>>(W1, W2, w1p, w2p);
  fused_ensemble_kernel<<<NQ * (B_TOTAL / BT), 256, 0, stream>>>(
      state, action, w1p, b1, w2p, b2, W3, b3, out);
}